// Round 11
// baseline (342.992 us; speedup 1.0000x reference)
//
#include <hip/hip_runtime.h>
#include <hip/hip_bf16.h>

// Problem constants (SpatialGraphConvolution_21251498180686)
#define NN 10000      // nodes per graph
#define EE 320000     // edges (before self-loops)
#define BB 4          // batch (graphs share edge structure)
#define F0 256        // input feat
#define F1 256        // hidden feat
#define F2 128        // output feat
#define ETOT (EE + NN)

typedef __attribute__((ext_vector_type(8))) short bf16x8;
typedef __attribute__((ext_vector_type(4))) float f32x4;
typedef unsigned short us8 __attribute__((ext_vector_type(8)));

__device__ inline unsigned short f2bf_rn(float f) {
    unsigned int u = __float_as_uint(f);
    unsigned int r = (u + 0x7fffu + ((u >> 16) & 1u)) >> 16;
    return (unsigned short)r;
}
__device__ inline float bf2f(unsigned short s) {
    return __uint_as_float(((unsigned int)s) << 16);
}

// ---------------------------------------------------------------------------
// CSR build (by dst) — int inputs arrive as int32.
// ---------------------------------------------------------------------------
__global__ void count_kernel(const int* __restrict__ ei, int* __restrict__ deg) {
    int id = blockIdx.x * blockDim.x + threadIdx.x;
    if (id >= ETOT) return;
    int dst = (id < EE) ? ei[EE + id] : (id - EE);
    atomicAdd(&deg[dst], 1);
}

__global__ void scan_kernel(const int* __restrict__ deg, int* __restrict__ rowstart) {
    __shared__ int part[256];
    int t = threadIdx.x;
    const int CH = (NN + 255) / 256;  // 40
    int lo = t * CH, hi = min(lo + CH, NN);
    int s = 0;
    for (int i = lo; i < hi; i++) s += deg[i];
    part[t] = s;
    __syncthreads();
    for (int off = 1; off < 256; off <<= 1) {
        int v = (t >= off) ? part[t - off] : 0;
        __syncthreads();
        part[t] += v;
        __syncthreads();
    }
    int run = (t == 0) ? 0 : part[t - 1];
    for (int i = lo; i < hi; i++) { int d = deg[i]; rowstart[i] = run; run += d; }
    if (t == 255) rowstart[NN] = run;
}

__global__ void scatter_kernel(const int* __restrict__ ei,
                               const int* __restrict__ rowstart,
                               int* __restrict__ fill,
                               int* __restrict__ sorted_src) {
    int id = blockIdx.x * blockDim.x + threadIdx.x;
    if (id >= ETOT) return;
    int src, dst;
    if (id < EE) { src = ei[id]; dst = ei[EE + id]; }
    else         { src = dst = id - EE; }
    int pos = rowstart[dst] + atomicAdd(&fill[dst], 1);
    sorted_src[pos] = src;
}

// ---------------------------------------------------------------------------
// Split fp32 -> [hi|lo] bf16 halves. ILV=1: input row r = b*NN+n is written
// to output row ri = n*4+b (the interleaved M-layout used everywhere).
// ---------------------------------------------------------------------------
template <int ILV>
__global__ __launch_bounds__(256) void conv_split(const float* __restrict__ in,
                                                  unsigned short* __restrict__ out2,
                                                  int rows, int K) {
    int q = K >> 2;
    int id = blockIdx.x * blockDim.x + threadIdx.x;
    if (id >= rows * q) return;
    int r = id / q;
    int c4 = (id - r * q) << 2;
    float4 v = *(const float4*)(in + (size_t)r * K + c4);
    ushort4 hi, lo;
    hi.x = f2bf_rn(v.x); lo.x = f2bf_rn(v.x - bf2f(hi.x));
    hi.y = f2bf_rn(v.y); lo.y = f2bf_rn(v.y - bf2f(hi.y));
    hi.z = f2bf_rn(v.z); lo.z = f2bf_rn(v.z - bf2f(hi.z));
    hi.w = f2bf_rn(v.w); lo.w = f2bf_rn(v.w - bf2f(hi.w));
    int ro = r;
    if (ILV) {
        int b = r / NN, n = r - b * NN;
        ro = n * 4 + b;
    }
    unsigned short* o = out2 + (size_t)ro * 2 * K;
    *(ushort4*)(o + c4) = hi;
    *(ushort4*)(o + K + c4) = lo;
}

// ---------------------------------------------------------------------------
// R10 GEMM (unchanged; row-agnostic so it works on ri-interleaved rows):
// register-prefetch double-buffered split-bf16 MFMA GEMM, A read once,
// 3 split terms per chunk (Ah*Bh + Al*Bh + Ah*Bl). Tile 128x128, 8 chunks.
// Fused partial al via atomicAdd (2 contributors, deterministic).
// ---------------------------------------------------------------------------
template <int NT>
__global__ __launch_bounds__(256) void gemm_db(
    const unsigned short* __restrict__ A2,   // [M][512] = [hi(256)|lo(256)]
    const unsigned short* __restrict__ B2,   // [NT][512]
    unsigned short* __restrict__ C,          // [M][NT] bf16
    const float* __restrict__ asrc,          // [NT]
    const float* __restrict__ adst,          // [NT]
    float* __restrict__ als,                 // [M] (pre-zeroed; atomicAdd)
    float* __restrict__ ald,                 // [M]
    int M) {
    __shared__ unsigned short sbuf[20480];   // 4 tiles x 128 x 40 shorts = 40KB
    unsigned short* Ah = sbuf;
    unsigned short* Al = sbuf + 5120;
    unsigned short* Bh = sbuf + 10240;
    unsigned short* Bl = sbuf + 15360;

    int tid = threadIdx.x;
    int wave = tid >> 6, lane = tid & 63;
    int wm = wave & 1, wn = wave >> 1;
    int lq = lane >> 4, lm = lane & 15;
    int bm = blockIdx.x * 128;
    int bn = blockIdx.y * 128;

    f32x4 acc[4][4];
#pragma unroll
    for (int i = 0; i < 4; i++)
#pragma unroll
        for (int j = 0; j < 4; j++) {
            acc[i][j][0] = 0.f; acc[i][j][1] = 0.f;
            acc[i][j][2] = 0.f; acc[i][j][3] = 0.f;
        }

    int r0 = tid >> 2, sub = tid & 3;
    int ar0 = min(bm + r0, M - 1), ar1 = min(bm + r0 + 64, M - 1);
    const unsigned short* aSrc0 = A2 + (size_t)ar0 * 512 + sub * 8;
    const unsigned short* aSrc1 = A2 + (size_t)ar1 * 512 + sub * 8;
    const unsigned short* bSrc0 = B2 + (size_t)(bn + r0) * 512 + sub * 8;
    const unsigned short* bSrc1 = B2 + (size_t)(bn + r0 + 64) * 512 + sub * 8;
    int ld0 = r0 * 40 + sub * 8;
    int ld1 = (r0 + 64) * 40 + sub * 8;

    uint4 pAh0, pAh1, pAl0, pAl1, pBh0, pBh1, pBl0, pBl1;

    auto loadreg = [&](int c) {
        int o = c * 32;
        pAh0 = *(const uint4*)(aSrc0 + o);       pAh1 = *(const uint4*)(aSrc1 + o);
        pAl0 = *(const uint4*)(aSrc0 + 256 + o); pAl1 = *(const uint4*)(aSrc1 + 256 + o);
        pBh0 = *(const uint4*)(bSrc0 + o);       pBh1 = *(const uint4*)(bSrc1 + o);
        pBl0 = *(const uint4*)(bSrc0 + 256 + o); pBl1 = *(const uint4*)(bSrc1 + 256 + o);
    };
    auto writereg = [&]() {
        *(uint4*)(Ah + ld0) = pAh0; *(uint4*)(Ah + ld1) = pAh1;
        *(uint4*)(Al + ld0) = pAl0; *(uint4*)(Al + ld1) = pAl1;
        *(uint4*)(Bh + ld0) = pBh0; *(uint4*)(Bh + ld1) = pBh1;
        *(uint4*)(Bl + ld0) = pBl0; *(uint4*)(Bl + ld1) = pBl1;
    };

    loadreg(0);
#pragma unroll 1
    for (int c = 0; c < 8; c++) {
        __syncthreads();
        writereg();
        __syncthreads();
        if (c < 7) loadreg(c + 1);

        bf16x8 afh[4], afl[4];
#pragma unroll
        for (int i = 0; i < 4; i++) {
            int row = wm * 64 + i * 16 + lm;
            afh[i] = *(const bf16x8*)(Ah + row * 40 + lq * 8);
            afl[i] = *(const bf16x8*)(Al + row * 40 + lq * 8);
        }
#pragma unroll
        for (int j = 0; j < 4; j++) {
            int row = wn * 64 + j * 16 + lm;
            bf16x8 bh = *(const bf16x8*)(Bh + row * 40 + lq * 8);
            bf16x8 bl = *(const bf16x8*)(Bl + row * 40 + lq * 8);
#pragma unroll
            for (int i = 0; i < 4; i++) {
                acc[i][j] = __builtin_amdgcn_mfma_f32_16x16x32_bf16(afh[i], bh, acc[i][j], 0, 0, 0);
                acc[i][j] = __builtin_amdgcn_mfma_f32_16x16x32_bf16(afl[i], bh, acc[i][j], 0, 0, 0);
                acc[i][j] = __builtin_amdgcn_mfma_f32_16x16x32_bf16(afh[i], bl, acc[i][j], 0, 0, 0);
            }
        }
    }

    __syncthreads();

    unsigned short* Cs = sbuf;   // [128][136]
#pragma unroll
    for (int i = 0; i < 4; i++) {
#pragma unroll
        for (int rr = 0; rr < 4; rr++) {
            int row = wm * 64 + i * 16 + lq * 4 + rr;
#pragma unroll
            for (int j = 0; j < 4; j++)
                Cs[row * 136 + wn * 64 + j * 16 + lm] = f2bf_rn(acc[i][j][rr]);
        }
    }
    __syncthreads();

    {
        int r = tid >> 1;
        int cl = (tid & 1) * 64;
        float s = 0.f, d = 0.f;
#pragma unroll
        for (int c8 = 0; c8 < 8; c8++) {
            bf16x8 v8 = *(const bf16x8*)(Cs + r * 136 + cl + c8 * 8);
#pragma unroll
            for (int u = 0; u < 8; u++) {
                float v = bf2f((unsigned short)v8[u]);
                s += v * asrc[bn + cl + c8 * 8 + u];
                d += v * adst[bn + cl + c8 * 8 + u];
            }
        }
        s += __shfl_xor(s, 1); d += __shfl_xor(d, 1);
        if ((tid & 1) == 0 && (bm + r) < M) {
            atomicAdd(&als[bm + r], s);
            atomicAdd(&ald[bm + r], d);
        }
    }

#pragma unroll
    for (int k = 0; k < 8; k++) {
        int u = k * 256 + tid;
        int row = u >> 4, q = u & 15;
        if (bm + row < M)
            *(uint4*)(C + (size_t)(bm + row) * NT + bn + q * 8) = *(const uint4*)(Cs + row * 136 + q * 8);
    }
}

// ---------------------------------------------------------------------------
// R11 batched agg: ONE wave per node n, all 4 graphs at once.
// Layouts (all ri = n*4+b interleaved): h[ri][F] bf16, als/ald[ri].
// Lane l: graph g = l>>4, feature block fb = l&15 (FB = F/16 features).
// Per edge: 4 graph-rows are 2KB contiguous -> lane loads its 32B (F=256,
// 2x uint4) or 16B (F=128, 1x uint4). Weights: one float4 als gather gives
// all 4 graphs; broadcast via 4 shfl + 2 cndmask selects.
// 4-edge zero-padded bursts (pad lanes have ex4=0, srcj=0 -> w=0).
// OUTMODE 0: fp32 out [B][N][F] standard. OUTMODE 1: split-bf16 [ri][2F].
// ---------------------------------------------------------------------------
template <int F, int OUTMODE>
__global__ __launch_bounds__(256) void agg_batched(
    const unsigned short* __restrict__ h,
    const float* __restrict__ als,
    const float* __restrict__ ald,
    const int* __restrict__ rowstart,
    const int* __restrict__ sorted_src,
    const float* __restrict__ bias,
    float* __restrict__ out,
    unsigned short* __restrict__ out2) {
    constexpr int FB = F / 16;   // features per lane (16 or 8)
    constexpr int NL = FB / 8;   // uint4 loads per edge (2 or 1)

    int n = blockIdx.x * 4 + (threadIdx.x >> 6);
    int lane = threadIdx.x & 63;
    int g = lane >> 4, fb = lane & 15;

    float4 ald4 = *(const float4*)(ald + (size_t)n * 4);
    int rs = rowstart[n];
    int deg = rowstart[n + 1] - rs;

    float acc[FB];
#pragma unroll
    for (int u = 0; u < FB; u++) acc[u] = 0.f;
    float4 sum4 = make_float4(0.f, 0.f, 0.f, 0.f);

    for (int c0 = 0; c0 < deg; c0 += 64) {
        int j = c0 + lane;
        float4 ex4 = make_float4(0.f, 0.f, 0.f, 0.f);
        int srcj = 0;
        if (j < deg) {
            srcj = sorted_src[rs + j];
            float4 a4 = *(const float4*)(als + (size_t)srcj * 4);
            float e;
            e = a4.x + ald4.x; e = e > 0.f ? e : 0.2f * e; ex4.x = __expf(e);
            e = a4.y + ald4.y; e = e > 0.f ? e : 0.2f * e; ex4.y = __expf(e);
            e = a4.z + ald4.z; e = e > 0.f ? e : 0.2f * e; ex4.z = __expf(e);
            e = a4.w + ald4.w; e = e > 0.f ? e : 0.2f * e; ex4.w = __expf(e);
        }
        sum4.x += ex4.x; sum4.y += ex4.y; sum4.z += ex4.z; sum4.w += ex4.w;

        int cnt = min(64, deg - c0);
        for (int bse = 0; bse < cnt; bse += 4) {
            int sj[4]; float wsel[4];
#pragma unroll
            for (int i = 0; i < 4; i++) {
                sj[i] = __shfl(srcj, bse + i);
                float w0 = __shfl(ex4.x, bse + i), w1 = __shfl(ex4.y, bse + i);
                float w2 = __shfl(ex4.z, bse + i), w3 = __shfl(ex4.w, bse + i);
                float wa = (g & 1) ? w1 : w0;
                float wb = (g & 1) ? w3 : w2;
                wsel[i] = (g & 2) ? wb : wa;
            }
            us8 r[4][NL];
#pragma unroll
            for (int i = 0; i < 4; i++) {
                const unsigned short* p = h + ((size_t)sj[i] * 4 + g) * F + fb * FB;
#pragma unroll
                for (int l = 0; l < NL; l++) r[i][l] = *(const us8*)(p + l * 8);
            }
#pragma unroll
            for (int i = 0; i < 4; i++)
#pragma unroll
                for (int l = 0; l < NL; l++)
#pragma unroll
                    for (int u = 0; u < 8; u++)
                        acc[l * 8 + u] += wsel[i] * bf2f((unsigned short)r[i][l][u]);
        }
    }

#pragma unroll
    for (int off = 32; off; off >>= 1) {
        sum4.x += __shfl_xor(sum4.x, off);
        sum4.y += __shfl_xor(sum4.y, off);
        sum4.z += __shfl_xor(sum4.z, off);
        sum4.w += __shfl_xor(sum4.w, off);
    }
    float sa = (g & 1) ? sum4.y : sum4.x;
    float sb = (g & 1) ? sum4.w : sum4.z;
    float sg = (g & 2) ? sb : sa;
    float inv = 1.0f / (sg + 1e-16f);

    float rv[FB];
#pragma unroll
    for (int u = 0; u < FB; u++) {
        float v = acc[u] * inv + bias[fb * FB + u];
        rv[u] = fmaxf(v, 0.f);
    }

    if (OUTMODE == 0) {
        float* o = out + ((size_t)g * NN + n) * F + fb * FB;
#pragma unroll
        for (int l = 0; l < FB / 4; l++)
            *(float4*)(o + l * 4) = make_float4(rv[l * 4], rv[l * 4 + 1], rv[l * 4 + 2], rv[l * 4 + 3]);
    } else {
        us8 hi8[NL], lo8[NL];
#pragma unroll
        for (int l = 0; l < NL; l++)
#pragma unroll
            for (int u = 0; u < 8; u++) {
                float v = rv[l * 8 + u];
                unsigned short hv = f2bf_rn(v);
                hi8[l][u] = hv;
                lo8[l][u] = f2bf_rn(v - bf2f(hv));
            }
        unsigned short* o = out2 + ((size_t)n * 4 + g) * 2 * F + fb * FB;
#pragma unroll
        for (int l = 0; l < NL; l++) {
            *(us8*)(o + l * 8) = hi8[l];
            *(us8*)(o + F + l * 8) = lo8[l];
        }
    }
}

// ---------------------------------------------------------------------------
extern "C" void kernel_launch(void* const* d_in, const int* in_sizes, int n_in,
                              void* d_out, int out_size, void* d_ws, size_t ws_size,
                              hipStream_t stream) {
    const float* x     = (const float*)d_in[0];
    const int*   ei    = (const int*)d_in[1];
    const float* W0    = (const float*)d_in[2];
    const float* b0    = (const float*)d_in[3];
    const float* asrc0 = (const float*)d_in[4];
    const float* adst0 = (const float*)d_in[5];
    const float* W1    = (const float*)d_in[6];
    const float* b1    = (const float*)d_in[7];
    const float* asrc1 = (const float*)d_in[8];
    const float* adst1 = (const float*)d_in[9];
    float* outp = (float*)d_out;

    const int M = BB * NN;  // 40000 (rows everywhere are ri = n*4+b interleaved)

    size_t off = 0;
    char* base = (char*)d_ws;
    auto alloc = [&](size_t bytes) {
        void* p = base + off;
        off += (bytes + 255) & ~(size_t)255;
        return p;
    };
    int*   deg        = (int*)alloc((size_t)NN * 4);   // deg+fill zeroed in ONE memset
    int*   fill       = (int*)alloc((size_t)NN * 4);
    int*   rowstart   = (int*)alloc((size_t)(NN + 1) * 4);
    int*   sorted_src = (int*)alloc((size_t)ETOT * 4);
    unsigned short* A2  = (unsigned short*)alloc((size_t)M * 512 * 2);  // x-split (ilv); reused as out0-split
    unsigned short* W02 = (unsigned short*)alloc((size_t)F1 * 512 * 2);
    unsigned short* W12 = (unsigned short*)alloc((size_t)F2 * 512 * 2);
    unsigned short* h   = (unsigned short*)alloc((size_t)M * F1 * 2);   // bf16 pre-agg features (ilv rows)
    float* als        = (float*)alloc((size_t)M * 4);   // als+ald contiguous (one memset)
    float* ald        = (float*)alloc((size_t)M * 4);

    hipMemsetAsync(deg, 0, (char*)fill - (char*)deg + (size_t)NN * 4, stream);

    int egrid = (ETOT + 255) / 256;
    count_kernel<<<egrid, 256, 0, stream>>>(ei, deg);
    scan_kernel<<<1, 256, 0, stream>>>(deg, rowstart);
    scatter_kernel<<<egrid, 256, 0, stream>>>(ei, rowstart, fill, sorted_src);

    conv_split<1><<<(M * (F0 / 4) + 255) / 256, 256, 0, stream>>>(x, A2, M, F0);
    conv_split<0><<<(F1 * (F0 / 4) + 255) / 256, 256, 0, stream>>>(W0, W02, F1, F0);
    conv_split<0><<<(F2 * (F1 / 4) + 255) / 256, 256, 0, stream>>>(W1, W12, F2, F1);

    int mtiles = (M + 127) / 128;          // 313
    int agrid = NN / 4;                    // 2500 blocks, 1 wave per node (4 graphs)

    // ----- layer 0 -----  (al fused into GEMM epilogue via atomicAdd)
    hipMemsetAsync(als, 0, (size_t)2 * M * 4, stream);
    gemm_db<F1><<<dim3(mtiles, F1 / 128), 256, 0, stream>>>(A2, W02, h, asrc0, adst0, als, ald, M);
    agg_batched<F1, 1><<<agrid, 256, 0, stream>>>(h, als, ald, rowstart, sorted_src, b0,
                                                  nullptr, A2 /* out0 split, ilv rows */);

    // ----- layer 1 -----
    hipMemsetAsync(als, 0, (size_t)2 * M * 4, stream);
    gemm_db<F2><<<dim3(mtiles, F2 / 128), 256, 0, stream>>>(A2, W12, h, asrc1, adst1, als, ald, M);
    agg_batched<F2, 0><<<agrid, 256, 0, stream>>>(h, als, ald, rowstart, sorted_src, b1,
                                                  outp, nullptr);
}

// Round 12
// 310.958 us; speedup vs baseline: 1.1030x; 1.1030x over previous
//
#include <hip/hip_runtime.h>
#include <hip/hip_bf16.h>

// Problem constants (SpatialGraphConvolution_21251498180686)
#define NN 10000      // nodes per graph
#define EE 320000     // edges (before self-loops)
#define BB 4          // batch (graphs share edge structure)
#define F0 256        // input feat
#define F1 256        // hidden feat
#define F2 128        // output feat
#define ETOT (EE + NN)

typedef __attribute__((ext_vector_type(8))) short bf16x8;
typedef __attribute__((ext_vector_type(4))) float f32x4;
typedef unsigned short us8 __attribute__((ext_vector_type(8)));

__device__ inline unsigned short f2bf_rn(float f) {
    unsigned int u = __float_as_uint(f);
    unsigned int r = (u + 0x7fffu + ((u >> 16) & 1u)) >> 16;
    return (unsigned short)r;
}
__device__ inline float bf2f(unsigned short s) {
    return __uint_as_float(((unsigned int)s) << 16);
}

// ---------------------------------------------------------------------------
// CSR build (by dst) — int inputs arrive as int32.
// ---------------------------------------------------------------------------
__global__ void count_kernel(const int* __restrict__ ei, int* __restrict__ deg) {
    int id = blockIdx.x * blockDim.x + threadIdx.x;
    if (id >= ETOT) return;
    int dst = (id < EE) ? ei[EE + id] : (id - EE);
    atomicAdd(&deg[dst], 1);
}

__global__ void scan_kernel(const int* __restrict__ deg, int* __restrict__ rowstart) {
    __shared__ int part[256];
    int t = threadIdx.x;
    const int CH = (NN + 255) / 256;  // 40
    int lo = t * CH, hi = min(lo + CH, NN);
    int s = 0;
    for (int i = lo; i < hi; i++) s += deg[i];
    part[t] = s;
    __syncthreads();
    for (int off = 1; off < 256; off <<= 1) {
        int v = (t >= off) ? part[t - off] : 0;
        __syncthreads();
        part[t] += v;
        __syncthreads();
    }
    int run = (t == 0) ? 0 : part[t - 1];
    for (int i = lo; i < hi; i++) { int d = deg[i]; rowstart[i] = run; run += d; }
    if (t == 255) rowstart[NN] = run;
}

__global__ void scatter_kernel(const int* __restrict__ ei,
                               const int* __restrict__ rowstart,
                               int* __restrict__ fill,
                               int* __restrict__ sorted_src) {
    int id = blockIdx.x * blockDim.x + threadIdx.x;
    if (id >= ETOT) return;
    int src, dst;
    if (id < EE) { src = ei[id]; dst = ei[EE + id]; }
    else         { src = dst = id - EE; }
    int pos = rowstart[dst] + atomicAdd(&fill[dst], 1);
    sorted_src[pos] = src;
}

// ---------------------------------------------------------------------------
// Fused W0+W1 split (both K=256): rows 0..255 -> W02, 256..383 -> W12.
// ---------------------------------------------------------------------------
__global__ __launch_bounds__(256) void conv_split_w(const float* __restrict__ W0,
                                                    const float* __restrict__ W1,
                                                    unsigned short* __restrict__ W02,
                                                    unsigned short* __restrict__ W12) {
    int id = blockIdx.x * 256 + threadIdx.x;
    if (id >= (F1 + F2) * 64) return;
    int r = id >> 6, c4 = (id & 63) << 2;
    const float* src;
    unsigned short* dst;
    if (r < F1) { src = W0 + (size_t)r * 256;        dst = W02 + (size_t)r * 512; }
    else        { src = W1 + (size_t)(r - F1) * 256; dst = W12 + (size_t)(r - F1) * 512; }
    float4 v = *(const float4*)(src + c4);
    ushort4 hi, lo;
    hi.x = f2bf_rn(v.x); lo.x = f2bf_rn(v.x - bf2f(hi.x));
    hi.y = f2bf_rn(v.y); lo.y = f2bf_rn(v.y - bf2f(hi.y));
    hi.z = f2bf_rn(v.z); lo.z = f2bf_rn(v.z - bf2f(hi.z));
    hi.w = f2bf_rn(v.w); lo.w = f2bf_rn(v.w - bf2f(hi.w));
    *(ushort4*)(dst + c4) = hi;
    *(ushort4*)(dst + 256 + c4) = lo;
}

// ---------------------------------------------------------------------------
// R12 GEMM: 64x128 tile (grid 625 x NT/128 -> 1250/625 blocks, 30KB LDS,
// 5 blocks/CU), register-prefetch double-buffered, split-bf16 3-term
// (Ah*Bh + Al*Bh + Ah*Bl). XF32=1: A input is raw fp32 (x) — loads stage
// fp32 into regs, conversion happens in writereg (prefetch stays async).
// Fused al epilogue: per-column-tile PARTIAL dot -> als2/ald2[row][2],
// slot = blockIdx.y (plain stores, no atomics, no pre-zeroing; NT=128
// writes zero to slot 1). M = 625*64 exactly -> no bounds checks.
// ---------------------------------------------------------------------------
template <int NT, int XF32>
__global__ __launch_bounds__(256) void gemm_db(
    const float* __restrict__ Af,            // fp32 A [M][256] (XF32=1)
    const unsigned short* __restrict__ A2,   // split A [M][512] (XF32=0)
    const unsigned short* __restrict__ B2,   // [NT][512]
    unsigned short* __restrict__ C,          // [M][NT] bf16
    const float* __restrict__ asrc,          // [NT]
    const float* __restrict__ adst,          // [NT]
    float* __restrict__ als2,                // [M][2]
    float* __restrict__ ald2) {              // [M][2]
    __shared__ unsigned short sbuf[15360];   // Ah 2560 | Al 2560 | Bh 5120 | Bl 5120
    unsigned short* Ah = sbuf;
    unsigned short* Al = sbuf + 2560;
    unsigned short* Bh = sbuf + 5120;
    unsigned short* Bl = sbuf + 10240;

    int tid = threadIdx.x;
    int wave = tid >> 6, lane = tid & 63;
    int wm = wave & 1, wn = wave >> 1;
    int lq = lane >> 4, lm = lane & 15;
    int bm = blockIdx.x * 64;
    int by = blockIdx.y;
    int bn = by * 128;

    f32x4 acc[2][4];
#pragma unroll
    for (int i = 0; i < 2; i++)
#pragma unroll
        for (int j = 0; j < 4; j++) {
            acc[i][j][0] = 0.f; acc[i][j][1] = 0.f;
            acc[i][j][2] = 0.f; acc[i][j][3] = 0.f;
        }

    // staging: thread t covers A row r0 (0..63) sub-unit sub (8 elems),
    // and B rows r0, r0+64 same sub-unit.
    int r0 = tid >> 2, sub = tid & 3;
    const unsigned short* aSrc2 = A2 + (size_t)(bm + r0) * 512 + sub * 8;
    const float* aSrcF = Af + (size_t)(bm + r0) * 256 + sub * 8;
    const unsigned short* bSrc0 = B2 + (size_t)(bn + r0) * 512 + sub * 8;
    const unsigned short* bSrc1 = B2 + (size_t)(bn + r0 + 64) * 512 + sub * 8;
    int lda = r0 * 40 + sub * 8;
    int ldb0 = r0 * 40 + sub * 8;
    int ldb1 = (r0 + 64) * 40 + sub * 8;

    uint4 pAh, pAl, pBh0, pBh1, pBl0, pBl1;
    float4 pF0, pF1;

    auto loadreg = [&](int c) {
        int o = c * 32;
        if (XF32) {
            pF0 = *(const float4*)(aSrcF + o);
            pF1 = *(const float4*)(aSrcF + o + 4);
        } else {
            pAh = *(const uint4*)(aSrc2 + o);
            pAl = *(const uint4*)(aSrc2 + 256 + o);
        }
        pBh0 = *(const uint4*)(bSrc0 + o);       pBh1 = *(const uint4*)(bSrc1 + o);
        pBl0 = *(const uint4*)(bSrc0 + 256 + o); pBl1 = *(const uint4*)(bSrc1 + 256 + o);
    };
    auto writereg = [&]() {
        if (XF32) {
            float fa[8];
            *(float4*)&fa[0] = pF0; *(float4*)&fa[4] = pF1;
            us8 hs, ls;
#pragma unroll
            for (int u = 0; u < 8; u++) {
                unsigned short hv = f2bf_rn(fa[u]);
                hs[u] = hv;
                ls[u] = f2bf_rn(fa[u] - bf2f(hv));
            }
            *(us8*)(Ah + lda) = hs;
            *(us8*)(Al + lda) = ls;
        } else {
            *(uint4*)(Ah + lda) = pAh;
            *(uint4*)(Al + lda) = pAl;
        }
        *(uint4*)(Bh + ldb0) = pBh0; *(uint4*)(Bh + ldb1) = pBh1;
        *(uint4*)(Bl + ldb0) = pBl0; *(uint4*)(Bl + ldb1) = pBl1;
    };

    loadreg(0);
#pragma unroll 1
    for (int c = 0; c < 8; c++) {
        __syncthreads();          // prior chunk's ds_reads complete
        writereg();
        __syncthreads();          // staged data visible
        if (c < 7) loadreg(c + 1);  // next chunk's global loads fly during MFMA

        bf16x8 afh[2], afl[2];
#pragma unroll
        for (int i = 0; i < 2; i++) {
            int row = wm * 32 + i * 16 + lm;
            afh[i] = *(const bf16x8*)(Ah + row * 40 + lq * 8);
            afl[i] = *(const bf16x8*)(Al + row * 40 + lq * 8);
        }
#pragma unroll
        for (int j = 0; j < 4; j++) {
            int row = wn * 64 + j * 16 + lm;
            bf16x8 bh = *(const bf16x8*)(Bh + row * 40 + lq * 8);
            bf16x8 bl = *(const bf16x8*)(Bl + row * 40 + lq * 8);
#pragma unroll
            for (int i = 0; i < 2; i++) {
                acc[i][j] = __builtin_amdgcn_mfma_f32_16x16x32_bf16(afh[i], bh, acc[i][j], 0, 0, 0);
                acc[i][j] = __builtin_amdgcn_mfma_f32_16x16x32_bf16(afl[i], bh, acc[i][j], 0, 0, 0);
                acc[i][j] = __builtin_amdgcn_mfma_f32_16x16x32_bf16(afh[i], bl, acc[i][j], 0, 0, 0);
            }
        }
    }

    __syncthreads();   // all LDS reads done; Cs aliases sbuf

    // Epilogue. C/D layout: col = lane&15, row = (lane>>4)*4 + reg.
    unsigned short* Cs = sbuf;   // [64][136] = 8704 shorts, fits
#pragma unroll
    for (int i = 0; i < 2; i++) {
#pragma unroll
        for (int rr = 0; rr < 4; rr++) {
            int row = wm * 32 + i * 16 + lq * 4 + rr;
#pragma unroll
            for (int j = 0; j < 4; j++)
                Cs[row * 136 + wn * 64 + j * 16 + lm] = f2bf_rn(acc[i][j][rr]);
        }
    }
    __syncthreads();

    // fused PARTIAL al over this 128-col tile: 4 threads/row, 32 cols each
    {
        int r = tid >> 2;
        int cseg = (tid & 3) * 32;
        float s = 0.f, d = 0.f;
#pragma unroll
        for (int c8 = 0; c8 < 4; c8++) {
            bf16x8 v8 = *(const bf16x8*)(Cs + r * 136 + cseg + c8 * 8);
#pragma unroll
            for (int u = 0; u < 8; u++) {
                float v = bf2f((unsigned short)v8[u]);
                s += v * asrc[bn + cseg + c8 * 8 + u];
                d += v * adst[bn + cseg + c8 * 8 + u];
            }
        }
        s += __shfl_xor(s, 1); d += __shfl_xor(d, 1);
        s += __shfl_xor(s, 2); d += __shfl_xor(d, 2);
        if ((tid & 3) == 0) {
            als2[(size_t)(bm + r) * 2 + by] = s;
            ald2[(size_t)(bm + r) * 2 + by] = d;
        }
        if (NT == 128 && (tid & 3) == 1) {   // single col-tile: zero slot 1
            als2[(size_t)(bm + r) * 2 + 1] = 0.f;
            ald2[(size_t)(bm + r) * 2 + 1] = 0.f;
        }
    }

    // coalesced C store: 64 rows x 16 uint4
#pragma unroll
    for (int k = 0; k < 4; k++) {
        int u = k * 256 + tid;
        int row = u >> 4, q = u & 15;
        *(uint4*)(C + (size_t)(bm + row) * NT + bn + q * 8) = *(const uint4*)(Cs + row * 136 + q * 8);
    }
}

// ---------------------------------------------------------------------------
// Fused attention softmax + aggregate + bias + relu (bf16 h gather).
// R10-proven b-major structure: one wave per (graph b, dst node n);
// 16-wide load bursts. als/ald are [row][2] partials -> sum the two slots.
// OUTMODE 0: fp32 out.  OUTMODE 1: split-bf16 [M][2F] feeding next GEMM.
// ---------------------------------------------------------------------------
template <int F, int OUTMODE>
__global__ __launch_bounds__(256) void agg_kernel(const unsigned short* __restrict__ h,
                                                  const float* __restrict__ als2,
                                                  const float* __restrict__ ald2,
                                                  const int* __restrict__ rowstart,
                                                  const int* __restrict__ sorted_src,
                                                  const float* __restrict__ bias,
                                                  float* __restrict__ out,
                                                  unsigned short* __restrict__ out2) {
    constexpr int V = F / 64;
    typedef unsigned short usv __attribute__((ext_vector_type(V)));
    typedef float fvec __attribute__((ext_vector_type(V)));

    int wid = (blockIdx.x * blockDim.x + threadIdx.x) >> 6;  // 0..B*N-1
    int lane = threadIdx.x & 63;
    int b = wid / NN;
    int n = wid - b * NN;

    const float2* als_b = (const float2*)als2 + (size_t)b * NN;
    float2 d2 = ((const float2*)ald2)[wid];
    float aldn = d2.x + d2.y;
    int rs = rowstart[n];
    int deg = rowstart[n + 1] - rs;
    const unsigned short* hb = h + (size_t)b * NN * F;

    fvec acc;
#pragma unroll
    for (int u = 0; u < V; u++) acc[u] = 0.f;
    float sum = 0.f;

    for (int c0 = 0; c0 < deg; c0 += 64) {
        int j = c0 + lane;
        float ex = 0.f;
        int srcj = 0;
        if (j < deg) {
            srcj = sorted_src[rs + j];
            float2 a2 = als_b[srcj];
            float e = a2.x + a2.y + aldn;
            e = e > 0.f ? e : 0.2f * e;
            ex = __expf(e);
        }
        sum += ex;
        int cnt = min(64, deg - c0);

        int nfull = cnt >> 4;
        for (int g = 0; g < nfull; g++) {
            int bse = g << 4;
            int s[16]; float w[16];
#pragma unroll
            for (int i = 0; i < 16; i++) {
                s[i] = __shfl(srcj, bse + i);
                w[i] = __shfl(ex, bse + i);
            }
            usv r[16];
#pragma unroll
            for (int i = 0; i < 16; i++)
                r[i] = *(const usv*)(hb + (size_t)s[i] * F + lane * V);
#pragma unroll
            for (int i = 0; i < 16; i++)
#pragma unroll
                for (int u = 0; u < V; u++) acc[u] += w[i] * bf2f(r[i][u]);
        }
        for (int bse = nfull << 4; bse < cnt; bse += 4) {
            int s[4]; float w[4];
#pragma unroll
            for (int i = 0; i < 4; i++) {
                s[i] = __shfl(srcj, bse + i);
                w[i] = __shfl(ex, bse + i);
            }
            usv r[4];
#pragma unroll
            for (int i = 0; i < 4; i++)
                r[i] = *(const usv*)(hb + (size_t)s[i] * F + lane * V);
#pragma unroll
            for (int i = 0; i < 4; i++)
#pragma unroll
                for (int u = 0; u < V; u++) acc[u] += w[i] * bf2f(r[i][u]);
        }
    }
#pragma unroll
    for (int off = 32; off; off >>= 1) sum += __shfl_xor(sum, off);
    float inv = 1.0f / (sum + 1e-16f);

    fvec r;
#pragma unroll
    for (int u = 0; u < V; u++) {
        float v = acc[u] * inv + bias[lane * V + u];
        r[u] = fmaxf(v, 0.f);
    }
    if (OUTMODE == 0) {
        *(fvec*)(out + (size_t)wid * F + lane * V) = r;
    } else {
        ushort4 hi, lo;
        hi.x = f2bf_rn(r[0]); lo.x = f2bf_rn(r[0] - bf2f(hi.x));
        hi.y = f2bf_rn(r[1]); lo.y = f2bf_rn(r[1] - bf2f(hi.y));
        hi.z = f2bf_rn(r[2]); lo.z = f2bf_rn(r[2] - bf2f(hi.z));
        hi.w = f2bf_rn(r[3]); lo.w = f2bf_rn(r[3] - bf2f(hi.w));
        unsigned short* o = out2 + (size_t)wid * 2 * F;
        *(ushort4*)(o + lane * 4) = hi;
        *(ushort4*)(o + F + lane * 4) = lo;
    }
}

// ---------------------------------------------------------------------------
extern "C" void kernel_launch(void* const* d_in, const int* in_sizes, int n_in,
                              void* d_out, int out_size, void* d_ws, size_t ws_size,
                              hipStream_t stream) {
    const float* x     = (const float*)d_in[0];
    const int*   ei    = (const int*)d_in[1];
    const float* W0    = (const float*)d_in[2];
    const float* b0    = (const float*)d_in[3];
    const float* asrc0 = (const float*)d_in[4];
    const float* adst0 = (const float*)d_in[5];
    const float* W1    = (const float*)d_in[6];
    const float* b1    = (const float*)d_in[7];
    const float* asrc1 = (const float*)d_in[8];
    const float* adst1 = (const float*)d_in[9];
    float* outp = (float*)d_out;

    const int M = BB * NN;  // 40000 = 625 * 64 exactly

    size_t off = 0;
    char* base = (char*)d_ws;
    auto alloc = [&](size_t bytes) {
        void* p = base + off;
        off += (bytes + 255) & ~(size_t)255;
        return p;
    };
    int*   deg        = (int*)alloc((size_t)NN * 4);   // deg+fill zeroed in ONE memset
    int*   fill       = (int*)alloc((size_t)NN * 4);
    int*   rowstart   = (int*)alloc((size_t)(NN + 1) * 4);
    int*   sorted_src = (int*)alloc((size_t)ETOT * 4);
    unsigned short* A2  = (unsigned short*)alloc((size_t)M * 512 * 2);  // out0-split (layer-1 A)
    unsigned short* W02 = (unsigned short*)alloc((size_t)F1 * 512 * 2);
    unsigned short* W12 = (unsigned short*)alloc((size_t)F2 * 512 * 2);
    unsigned short* h   = (unsigned short*)alloc((size_t)M * F1 * 2);   // bf16 pre-agg features
    float* als2       = (float*)alloc((size_t)M * 2 * 4);  // [row][2] partials (no memset)
    float* ald2       = (float*)alloc((size_t)M * 2 * 4);

    hipMemsetAsync(deg, 0, (char*)fill - (char*)deg + (size_t)NN * 4, stream);

    int egrid = (ETOT + 255) / 256;
    count_kernel<<<egrid, 256, 0, stream>>>(ei, deg);
    scan_kernel<<<1, 256, 0, stream>>>(deg, rowstart);
    scatter_kernel<<<egrid, 256, 0, stream>>>(ei, rowstart, fill, sorted_src);

    conv_split_w<<<((F1 + F2) * 64 + 255) / 256, 256, 0, stream>>>(W0, W1, W02, W12);

    int wgrid = (M * 64) / 256;            // 10000 blocks, 1 wave per (b,node)

    // ----- layer 0 -----  (x-split fused into GEMM staging; al fused into epilogue)
    gemm_db<F1, 1><<<dim3(625, F1 / 128), 256, 0, stream>>>(x, nullptr, W02, h,
                                                            asrc0, adst0, als2, ald2);
    agg_kernel<F1, 1><<<wgrid, 256, 0, stream>>>(h, als2, ald2, rowstart, sorted_src, b0,
                                                 nullptr, A2 /* out0 split */);

    // ----- layer 1 -----
    gemm_db<F2, 0><<<dim3(625, F2 / 128), 256, 0, stream>>>(nullptr, A2, W12, h,
                                                            asrc1, adst1, als2, ald2);
    agg_kernel<F2, 0><<<wgrid, 256, 0, stream>>>(h, als2, ald2, rowstart, sorted_src, b1,
                                                 outp, nullptr);
}

// Round 13
// 304.735 us; speedup vs baseline: 1.1255x; 1.0204x over previous
//
#include <hip/hip_runtime.h>
#include <hip/hip_bf16.h>

// Problem constants (SpatialGraphConvolution_21251498180686)
#define NN 10000      // nodes per graph
#define EE 320000     // edges (before self-loops)
#define BB 4          // batch (graphs share edge structure)
#define F0 256        // input feat
#define F1 256        // hidden feat
#define F2 128        // output feat
#define ETOT (EE + NN)

typedef __attribute__((ext_vector_type(8))) short bf16x8;
typedef __attribute__((ext_vector_type(4))) float f32x4;
typedef unsigned short us8 __attribute__((ext_vector_type(8)));

__device__ inline unsigned short f2bf_rn(float f) {
    unsigned int u = __float_as_uint(f);
    unsigned int r = (u + 0x7fffu + ((u >> 16) & 1u)) >> 16;
    return (unsigned short)r;
}
__device__ inline float bf2f(unsigned short s) {
    return __uint_as_float(((unsigned int)s) << 16);
}

// ---------------------------------------------------------------------------
// CSR build (by dst) — int inputs arrive as int32.
// ---------------------------------------------------------------------------
__global__ void count_kernel(const int* __restrict__ ei, int* __restrict__ deg) {
    int id = blockIdx.x * blockDim.x + threadIdx.x;
    if (id >= ETOT) return;
    int dst = (id < EE) ? ei[EE + id] : (id - EE);
    atomicAdd(&deg[dst], 1);
}

__global__ void scan_kernel(const int* __restrict__ deg, int* __restrict__ rowstart) {
    __shared__ int part[256];
    int t = threadIdx.x;
    const int CH = (NN + 255) / 256;  // 40
    int lo = t * CH, hi = min(lo + CH, NN);
    int s = 0;
    for (int i = lo; i < hi; i++) s += deg[i];
    part[t] = s;
    __syncthreads();
    for (int off = 1; off < 256; off <<= 1) {
        int v = (t >= off) ? part[t - off] : 0;
        __syncthreads();
        part[t] += v;
        __syncthreads();
    }
    int run = (t == 0) ? 0 : part[t - 1];
    for (int i = lo; i < hi; i++) { int d = deg[i]; rowstart[i] = run; run += d; }
    if (t == 255) rowstart[NN] = run;
}

__global__ void scatter_kernel(const int* __restrict__ ei,
                               const int* __restrict__ rowstart,
                               int* __restrict__ fill,
                               int* __restrict__ sorted_src) {
    int id = blockIdx.x * blockDim.x + threadIdx.x;
    if (id >= ETOT) return;
    int src, dst;
    if (id < EE) { src = ei[id]; dst = ei[EE + id]; }
    else         { src = dst = id - EE; }
    int pos = rowstart[dst] + atomicAdd(&fill[dst], 1);
    sorted_src[pos] = src;
}

// ---------------------------------------------------------------------------
// Fused W0+W1 split (both K=256): rows 0..255 -> W02, 256..383 -> W12.
// ---------------------------------------------------------------------------
__global__ __launch_bounds__(256) void conv_split_w(const float* __restrict__ W0,
                                                    const float* __restrict__ W1,
                                                    unsigned short* __restrict__ W02,
                                                    unsigned short* __restrict__ W12) {
    int id = blockIdx.x * 256 + threadIdx.x;
    if (id >= (F1 + F2) * 64) return;
    int r = id >> 6, c4 = (id & 63) << 2;
    const float* src;
    unsigned short* dst;
    if (r < F1) { src = W0 + (size_t)r * 256;        dst = W02 + (size_t)r * 512; }
    else        { src = W1 + (size_t)(r - F1) * 256; dst = W12 + (size_t)(r - F1) * 512; }
    float4 v = *(const float4*)(src + c4);
    ushort4 hi, lo;
    hi.x = f2bf_rn(v.x); lo.x = f2bf_rn(v.x - bf2f(hi.x));
    hi.y = f2bf_rn(v.y); lo.y = f2bf_rn(v.y - bf2f(hi.y));
    hi.z = f2bf_rn(v.z); lo.z = f2bf_rn(v.z - bf2f(hi.z));
    hi.w = f2bf_rn(v.w); lo.w = f2bf_rn(v.w - bf2f(hi.w));
    *(ushort4*)(dst + c4) = hi;
    *(ushort4*)(dst + 256 + c4) = lo;
}

// ---------------------------------------------------------------------------
// R12 GEMM (unchanged, proven): 64x128 tile, register-prefetch double-buffer,
// split-bf16 3-term. XF32=1 fuses the fp32->split conversion into staging.
// Fused partial-al epilogue -> als2/ald2[row][2], slot=blockIdx.y.
// ---------------------------------------------------------------------------
template <int NT, int XF32>
__global__ __launch_bounds__(256) void gemm_db(
    const float* __restrict__ Af,
    const unsigned short* __restrict__ A2,
    const unsigned short* __restrict__ B2,
    unsigned short* __restrict__ C,
    const float* __restrict__ asrc,
    const float* __restrict__ adst,
    float* __restrict__ als2,
    float* __restrict__ ald2) {
    __shared__ unsigned short sbuf[15360];
    unsigned short* Ah = sbuf;
    unsigned short* Al = sbuf + 2560;
    unsigned short* Bh = sbuf + 5120;
    unsigned short* Bl = sbuf + 10240;

    int tid = threadIdx.x;
    int wave = tid >> 6, lane = tid & 63;
    int wm = wave & 1, wn = wave >> 1;
    int lq = lane >> 4, lm = lane & 15;
    int bm = blockIdx.x * 64;
    int by = blockIdx.y;
    int bn = by * 128;

    f32x4 acc[2][4];
#pragma unroll
    for (int i = 0; i < 2; i++)
#pragma unroll
        for (int j = 0; j < 4; j++) {
            acc[i][j][0] = 0.f; acc[i][j][1] = 0.f;
            acc[i][j][2] = 0.f; acc[i][j][3] = 0.f;
        }

    int r0 = tid >> 2, sub = tid & 3;
    const unsigned short* aSrc2 = A2 + (size_t)(bm + r0) * 512 + sub * 8;
    const float* aSrcF = Af + (size_t)(bm + r0) * 256 + sub * 8;
    const unsigned short* bSrc0 = B2 + (size_t)(bn + r0) * 512 + sub * 8;
    const unsigned short* bSrc1 = B2 + (size_t)(bn + r0 + 64) * 512 + sub * 8;
    int lda = r0 * 40 + sub * 8;
    int ldb0 = r0 * 40 + sub * 8;
    int ldb1 = (r0 + 64) * 40 + sub * 8;

    uint4 pAh, pAl, pBh0, pBh1, pBl0, pBl1;
    float4 pF0, pF1;

    auto loadreg = [&](int c) {
        int o = c * 32;
        if (XF32) {
            pF0 = *(const float4*)(aSrcF + o);
            pF1 = *(const float4*)(aSrcF + o + 4);
        } else {
            pAh = *(const uint4*)(aSrc2 + o);
            pAl = *(const uint4*)(aSrc2 + 256 + o);
        }
        pBh0 = *(const uint4*)(bSrc0 + o);       pBh1 = *(const uint4*)(bSrc1 + o);
        pBl0 = *(const uint4*)(bSrc0 + 256 + o); pBl1 = *(const uint4*)(bSrc1 + 256 + o);
    };
    auto writereg = [&]() {
        if (XF32) {
            float fa[8];
            *(float4*)&fa[0] = pF0; *(float4*)&fa[4] = pF1;
            us8 hs, ls;
#pragma unroll
            for (int u = 0; u < 8; u++) {
                unsigned short hv = f2bf_rn(fa[u]);
                hs[u] = hv;
                ls[u] = f2bf_rn(fa[u] - bf2f(hv));
            }
            *(us8*)(Ah + lda) = hs;
            *(us8*)(Al + lda) = ls;
        } else {
            *(uint4*)(Ah + lda) = pAh;
            *(uint4*)(Al + lda) = pAl;
        }
        *(uint4*)(Bh + ldb0) = pBh0; *(uint4*)(Bh + ldb1) = pBh1;
        *(uint4*)(Bl + ldb0) = pBl0; *(uint4*)(Bl + ldb1) = pBl1;
    };

    loadreg(0);
#pragma unroll 1
    for (int c = 0; c < 8; c++) {
        __syncthreads();
        writereg();
        __syncthreads();
        if (c < 7) loadreg(c + 1);

        bf16x8 afh[2], afl[2];
#pragma unroll
        for (int i = 0; i < 2; i++) {
            int row = wm * 32 + i * 16 + lm;
            afh[i] = *(const bf16x8*)(Ah + row * 40 + lq * 8);
            afl[i] = *(const bf16x8*)(Al + row * 40 + lq * 8);
        }
#pragma unroll
        for (int j = 0; j < 4; j++) {
            int row = wn * 64 + j * 16 + lm;
            bf16x8 bh = *(const bf16x8*)(Bh + row * 40 + lq * 8);
            bf16x8 bl = *(const bf16x8*)(Bl + row * 40 + lq * 8);
#pragma unroll
            for (int i = 0; i < 2; i++) {
                acc[i][j] = __builtin_amdgcn_mfma_f32_16x16x32_bf16(afh[i], bh, acc[i][j], 0, 0, 0);
                acc[i][j] = __builtin_amdgcn_mfma_f32_16x16x32_bf16(afl[i], bh, acc[i][j], 0, 0, 0);
                acc[i][j] = __builtin_amdgcn_mfma_f32_16x16x32_bf16(afh[i], bl, acc[i][j], 0, 0, 0);
            }
        }
    }

    __syncthreads();

    unsigned short* Cs = sbuf;   // [64][136]
#pragma unroll
    for (int i = 0; i < 2; i++) {
#pragma unroll
        for (int rr = 0; rr < 4; rr++) {
            int row = wm * 32 + i * 16 + lq * 4 + rr;
#pragma unroll
            for (int j = 0; j < 4; j++)
                Cs[row * 136 + wn * 64 + j * 16 + lm] = f2bf_rn(acc[i][j][rr]);
        }
    }
    __syncthreads();

    {
        int r = tid >> 2;
        int cseg = (tid & 3) * 32;
        float s = 0.f, d = 0.f;
#pragma unroll
        for (int c8 = 0; c8 < 4; c8++) {
            bf16x8 v8 = *(const bf16x8*)(Cs + r * 136 + cseg + c8 * 8);
#pragma unroll
            for (int u = 0; u < 8; u++) {
                float v = bf2f((unsigned short)v8[u]);
                s += v * asrc[bn + cseg + c8 * 8 + u];
                d += v * adst[bn + cseg + c8 * 8 + u];
            }
        }
        s += __shfl_xor(s, 1); d += __shfl_xor(d, 1);
        s += __shfl_xor(s, 2); d += __shfl_xor(d, 2);
        if ((tid & 3) == 0) {
            als2[(size_t)(bm + r) * 2 + by] = s;
            ald2[(size_t)(bm + r) * 2 + by] = d;
        }
        if (NT == 128 && (tid & 3) == 1) {
            als2[(size_t)(bm + r) * 2 + 1] = 0.f;
            ald2[(size_t)(bm + r) * 2 + 1] = 0.f;
        }
    }

#pragma unroll
    for (int k = 0; k < 4; k++) {
        int u = k * 256 + tid;
        int row = u >> 4, q = u & 15;
        *(uint4*)(C + (size_t)(bm + row) * NT + bn + q * 8) = *(const uint4*)(Cs + row * 136 + q * 8);
    }
}

// ---------------------------------------------------------------------------
// R13 agg: b-major (R10/R12-proven locality), but LPE = F/8 lanes per edge,
// each lane loading 16B (8 bf16 features) -> VMEM insts, shfl broadcasts,
// and addressing all halve (F=256) or quarter (F=128) vs R12 per edge.
// G = 64/LPE edges processed concurrently per slot; 8 slots in flight.
// Cross-edge-group merge at the end via shfl_xor(LPE..32).
// OUTMODE 0: fp32 out.  OUTMODE 1: split-bf16 [M][2F] feeding next GEMM.
// ---------------------------------------------------------------------------
template <int F, int OUTMODE>
__global__ __launch_bounds__(256) void agg_kernel(const unsigned short* __restrict__ h,
                                                  const float* __restrict__ als2,
                                                  const float* __restrict__ ald2,
                                                  const int* __restrict__ rowstart,
                                                  const int* __restrict__ sorted_src,
                                                  const float* __restrict__ bias,
                                                  float* __restrict__ out,
                                                  unsigned short* __restrict__ out2) {
    constexpr int LPE = F / 8;    // lanes covering one edge (32 or 16)
    constexpr int G = 64 / LPE;   // concurrent edges per slot (2 or 4)

    int wid = (blockIdx.x * blockDim.x + threadIdx.x) >> 6;  // 0..B*N-1
    int lane = threadIdx.x & 63;
    int b = wid / NN;
    int n = wid - b * NN;
    int g = lane / LPE;           // edge group
    int fb = lane % LPE;          // feature block (8 bf16)

    const float2* als_b = (const float2*)als2 + (size_t)b * NN;
    float2 d2 = ((const float2*)ald2)[wid];
    float aldn = d2.x + d2.y;
    int rs = rowstart[n];
    int deg = rowstart[n + 1] - rs;
    const unsigned short* hb = h + (size_t)b * NN * F;

    float acc[8];
#pragma unroll
    for (int u = 0; u < 8; u++) acc[u] = 0.f;
    float sum = 0.f;

    for (int c0 = 0; c0 < deg; c0 += 64) {
        int j = c0 + lane;
        float ex = 0.f;
        int srcj = 0;
        if (j < deg) {
            srcj = sorted_src[rs + j];
            float2 a2 = als_b[srcj];
            float e = a2.x + a2.y + aldn;
            e = e > 0.f ? e : 0.2f * e;
            ex = __expf(e);
        }
        sum += ex;
        int cnt = min(64, deg - c0);

        // bursts: 8 slots x G edges = 8G edges per burst (16 or 32)
        for (int bse = 0; bse < cnt; bse += 8 * G) {
            int s[8];
#pragma unroll
            for (int i = 0; i < 8; i++)
                s[i] = __shfl(srcj, bse + i * G + g);   // pad lanes: srcj=0, ex=0
            us8 r[8];
#pragma unroll
            for (int i = 0; i < 8; i++)
                r[i] = *(const us8*)(hb + (size_t)s[i] * F + fb * 8);
#pragma unroll
            for (int i = 0; i < 8; i++) {
                float w = __shfl(ex, bse + i * G + g);
#pragma unroll
                for (int u = 0; u < 8; u++)
                    acc[u] += w * bf2f((unsigned short)r[i][u]);
            }
        }
    }
    // softmax denominator: full 64-lane reduce
#pragma unroll
    for (int off = 32; off; off >>= 1) sum += __shfl_xor(sum, off);
    // merge edge groups: lanes with same fb across g hold partial acc
#pragma unroll
    for (int m = LPE; m < 64; m <<= 1)
#pragma unroll
        for (int u = 0; u < 8; u++) acc[u] += __shfl_xor(acc[u], m);

    float inv = 1.0f / (sum + 1e-16f);

    float rv[8];
#pragma unroll
    for (int u = 0; u < 8; u++) {
        float v = acc[u] * inv + bias[fb * 8 + u];
        rv[u] = fmaxf(v, 0.f);
    }

    if (g == 0) {
        if (OUTMODE == 0) {
            float* o = out + (size_t)wid * F + fb * 8;
            *(float4*)(o) = make_float4(rv[0], rv[1], rv[2], rv[3]);
            *(float4*)(o + 4) = make_float4(rv[4], rv[5], rv[6], rv[7]);
        } else {
            us8 hi8, lo8;
#pragma unroll
            for (int u = 0; u < 8; u++) {
                unsigned short hv = f2bf_rn(rv[u]);
                hi8[u] = hv;
                lo8[u] = f2bf_rn(rv[u] - bf2f(hv));
            }
            unsigned short* o = out2 + (size_t)wid * 2 * F + fb * 8;
            *(us8*)(o) = hi8;
            *(us8*)(o + F) = lo8;
        }
    }
}

// ---------------------------------------------------------------------------
extern "C" void kernel_launch(void* const* d_in, const int* in_sizes, int n_in,
                              void* d_out, int out_size, void* d_ws, size_t ws_size,
                              hipStream_t stream) {
    const float* x     = (const float*)d_in[0];
    const int*   ei    = (const int*)d_in[1];
    const float* W0    = (const float*)d_in[2];
    const float* b0    = (const float*)d_in[3];
    const float* asrc0 = (const float*)d_in[4];
    const float* adst0 = (const float*)d_in[5];
    const float* W1    = (const float*)d_in[6];
    const float* b1    = (const float*)d_in[7];
    const float* asrc1 = (const float*)d_in[8];
    const float* adst1 = (const float*)d_in[9];
    float* outp = (float*)d_out;

    const int M = BB * NN;  // 40000 = 625 * 64 exactly

    size_t off = 0;
    char* base = (char*)d_ws;
    auto alloc = [&](size_t bytes) {
        void* p = base + off;
        off += (bytes + 255) & ~(size_t)255;
        return p;
    };
    int*   deg        = (int*)alloc((size_t)NN * 4);   // deg+fill zeroed in ONE memset
    int*   fill       = (int*)alloc((size_t)NN * 4);
    int*   rowstart   = (int*)alloc((size_t)(NN + 1) * 4);
    int*   sorted_src = (int*)alloc((size_t)ETOT * 4);
    unsigned short* A2  = (unsigned short*)alloc((size_t)M * 512 * 2);  // out0-split (layer-1 A)
    unsigned short* W02 = (unsigned short*)alloc((size_t)F1 * 512 * 2);
    unsigned short* W12 = (unsigned short*)alloc((size_t)F2 * 512 * 2);
    unsigned short* h   = (unsigned short*)alloc((size_t)M * F1 * 2);   // bf16 pre-agg features
    float* als2       = (float*)alloc((size_t)M * 2 * 4);  // [row][2] partials (no memset)
    float* ald2       = (float*)alloc((size_t)M * 2 * 4);

    hipMemsetAsync(deg, 0, (char*)fill - (char*)deg + (size_t)NN * 4, stream);

    int egrid = (ETOT + 255) / 256;
    count_kernel<<<egrid, 256, 0, stream>>>(ei, deg);
    scan_kernel<<<1, 256, 0, stream>>>(deg, rowstart);
    scatter_kernel<<<egrid, 256, 0, stream>>>(ei, rowstart, fill, sorted_src);

    conv_split_w<<<((F1 + F2) * 64 + 255) / 256, 256, 0, stream>>>(W0, W1, W02, W12);

    int wgrid = (M * 64) / 256;            // 10000 blocks, 1 wave per (b,node)

    // ----- layer 0 -----  (x-split fused into GEMM staging; al fused into epilogue)
    gemm_db<F1, 1><<<dim3(625, F1 / 128), 256, 0, stream>>>(x, nullptr, W02, h,
                                                            asrc0, adst0, als2, ald2);
    agg_kernel<F1, 1><<<wgrid, 256, 0, stream>>>(h, als2, ald2, rowstart, sorted_src, b0,
                                                 nullptr, A2 /* out0 split */);

    // ----- layer 1 -----
    gemm_db<F2, 0><<<dim3(625, F2 / 128), 256, 0, stream>>>(nullptr, A2, W12, h,
                                                            asrc1, adst1, als2, ald2);
    agg_kernel<F2, 0><<<wgrid, 256, 0, stream>>>(h, als2, ald2, rowstart, sorted_src, b1,
                                                 outp, nullptr);
}